// Round 7
// baseline (157.835 us; speedup 1.0000x reference)
//
#include <hip/hip_runtime.h>

// Problem constants (from reference)
#define BATCH 2048
#define FDIM  1024
#define GTILE 16
#define F4    (FDIM / 4)                  // 256 float4 col-groups per row
#define CHUNKS 256
#define ROWS_PER_CHUNK (BATCH / CHUNKS)   // 8

// ws layout (in floats):
#define OFF_P1   0                        // [CHUNKS][FDIM] partial col sums of xf (1 MB)
#define OFF_MEAN 262144                   // [FDIM]
#define OFF_SC   263168                   // [FDIM] scale = wp/sd
#define OFF_CC   264192                   // [FDIM] mu*scale

__device__ __forceinline__ void v4add(float4& a, const float4& b) {
    a.x += b.x; a.y += b.y; a.z += b.z; a.w += b.w;
}

// 256 blocks x 256 threads: block = row chunk (8 rows), thread = col-group.
// Perfectly coalesced; writes per-chunk partial column sums.
__global__ void k1_partial_sum(const float4* __restrict__ xf, float4* __restrict__ p1) {
    const int tid = threadIdx.x;            // col-group
    const int chunk = blockIdx.x;           // 0..255
    const float4* p = xf + (size_t)chunk * ROWS_PER_CHUNK * F4 + tid;
    float4 s = {0.f, 0.f, 0.f, 0.f};
#pragma unroll
    for (int r = 0; r < ROWS_PER_CHUNK; ++r) v4add(s, p[r * F4]);
    p1[chunk * F4 + tid] = s;
}

// 256 blocks x 256 threads: block b owns col-group b (4 columns).
// Phase 1: tree-reduce the 256 chunk partials -> mean (no grid barrier).
// Phase 2: re-read the column (L2/L3-hot) for relu sum/sumsq, tree-reduce,
// write mean/sc/cc.
__global__ void k23_stats(const float4* __restrict__ xf,
                          const float* __restrict__ wp,
                          const float4* __restrict__ p1,
                          float4* __restrict__ mean,
                          float4* __restrict__ sc,
                          float4* __restrict__ cc) {
    __shared__ float4 rA[256], rB[256];    // 8 KB
    const int t = threadIdx.x;
    const int b = blockIdx.x;              // col-group

    // ---- mean of column-group b ----
    rA[t] = p1[t * F4 + b];                // chunk t's partial for col-group b
    __syncthreads();
    for (int off = 128; off > 0; off >>= 1) {
        if (t < off) v4add(rA[t], rA[t + off]);
        __syncthreads();
    }
    const float inv_n = 1.0f / (float)BATCH;
    float4 m = rA[0];                      // broadcast (conflict-free)
    m.x *= inv_n; m.y *= inv_n; m.z *= inv_n; m.w *= inv_n;
    if (t == 0) mean[b] = m;

    // ---- relu(x - mean) sum & sumsq over this thread's 8 rows ----
    const float4* p = xf + (size_t)t * ROWS_PER_CHUNK * F4 + b;
    float4 s = {0.f, 0.f, 0.f, 0.f};
    float4 q = {0.f, 0.f, 0.f, 0.f};
#pragma unroll
    for (int r = 0; r < ROWS_PER_CHUNK; ++r) {
        float4 v = p[r * F4];
        float rx = fmaxf(v.x - m.x, 0.f);
        float ry = fmaxf(v.y - m.y, 0.f);
        float rz = fmaxf(v.z - m.z, 0.f);
        float rw = fmaxf(v.w - m.w, 0.f);
        s.x += rx; s.y += ry; s.z += rz; s.w += rw;
        q.x += rx * rx; q.y += ry * ry; q.z += rz * rz; q.w += rw * rw;
    }
    __syncthreads();                       // rA[0] read by all before overwrite
    rA[t] = s; rB[t] = q;
    __syncthreads();
    for (int off = 128; off > 0; off >>= 1) {
        if (t < off) { v4add(rA[t], rA[t + off]); v4add(rB[t], rB[t + off]); }
        __syncthreads();
    }
    if (t == 0) {
        const float w = wp[0];
        float4 S = rA[0], Q = rB[0];
        float4 scale, cmb;
        float mu, var;
        mu = S.x * inv_n; var = (Q.x - S.x * mu) / (float)(BATCH - 1);
        scale.x = w * rsqrtf(var); cmb.x = mu * scale.x;
        mu = S.y * inv_n; var = (Q.y - S.y * mu) / (float)(BATCH - 1);
        scale.y = w * rsqrtf(var); cmb.y = mu * scale.y;
        mu = S.z * inv_n; var = (Q.z - S.z * mu) / (float)(BATCH - 1);
        scale.z = w * rsqrtf(var); cmb.z = mu * scale.z;
        mu = S.w * inv_n; var = (Q.w - S.w * mu) / (float)(BATCH - 1);
        scale.w = w * rsqrtf(var); cmb.w = mu * scale.w;
        sc[b] = scale;
        cc[b] = cmb;
    }
}

__global__ void k4_write(const float4* __restrict__ xf,
                         const float4* __restrict__ mean,
                         const float4* __restrict__ sc,
                         const float4* __restrict__ cc,
                         float4* __restrict__ out) {
    const int tid = threadIdx.x;     // 0..255
    const int row = blockIdx.x;      // 0..2047
    float4 m = mean[tid];
    float4 a = sc[tid];
    float4 c = cc[tid];
    float4 v = xf[(size_t)row * F4 + tid];
    float4 o;
    o.x = fmaxf(v.x - m.x, 0.f) * a.x - c.x;
    o.y = fmaxf(v.y - m.y, 0.f) * a.y - c.y;
    o.z = fmaxf(v.z - m.z, 0.f) * a.z - c.z;
    o.w = fmaxf(v.w - m.w, 0.f) * a.w - c.w;
    float4* dst = out + (size_t)row * (GTILE * F4) + tid;
#pragma unroll
    for (int g = 0; g < GTILE; ++g) {
        dst[g * F4] = o;
    }
}

extern "C" void kernel_launch(void* const* d_in, const int* in_sizes, int n_in,
                              void* d_out, int out_size, void* d_ws, size_t ws_size,
                              hipStream_t stream) {
    const float4* xf4 = (const float4*)d_in[0];
    const float* wp = (const float*)d_in[1];
    float* ws = (float*)d_ws;
    float4* out = (float4*)d_out;

    float4* p1   = (float4*)(ws + OFF_P1);
    float4* mean = (float4*)(ws + OFF_MEAN);
    float4* sc   = (float4*)(ws + OFF_SC);
    float4* cc   = (float4*)(ws + OFF_CC);

    k1_partial_sum<<<CHUNKS, 256, 0, stream>>>(xf4, p1);
    k23_stats<<<F4, 256, 0, stream>>>(xf4, wp, p1, mean, sc, cc);
    k4_write<<<BATCH, 256, 0, stream>>>(xf4, mean, sc, cc, out);
}